// Round 10
// baseline (207.188 us; speedup 1.0000x reference)
//
#include <hip/hip_runtime.h>

#define N_NODES 4096
#define F_IN 512
#define H_DIM 128
#define C_DIM 16
#define EPSF 1e-8f
#define LOG2E 1.4426950408889634f
#define SMAX 2.0f   // static softmax max: logits = cos/tau*log2e + log2(adj+eps) < 2 always
#define NKS0 8      // layer-0 K-splits
#define KLEN0 (N_NODES / NKS0)
#define NT0 (KLEN0 / 32)
#define NKS1 8      // layer-1 K-splits

typedef __attribute__((ext_vector_type(8))) short bf16x8;
typedef __attribute__((ext_vector_type(4))) short bf16x4;
typedef __attribute__((ext_vector_type(4))) float f32x4;

__device__ __forceinline__ ushort f2bf(float f){
  union { float f; unsigned u; } v; v.f = f;
  unsigned u = v.u;
  return (ushort)((u + 0x7fffu + ((u >> 16) & 1u)) >> 16);
}
__device__ __forceinline__ float bf2f(ushort h){
  union { unsigned u; float f; } v; v.u = ((unsigned)h) << 16;
  return v.f;
}

// ---------------------------------------------------------------------------
// K1: h = x @ W0 for 3 branches; row norms; write hn (bf16, row-major) and
//     hvT (bf16, transposed [3][128][4096]).
// ---------------------------------------------------------------------------
__global__ __launch_bounds__(128) void proj0_kernel(
    const float* __restrict__ x,
    const float* __restrict__ Wl, const float* __restrict__ Wh,
    const float* __restrict__ Wm,
    ushort* __restrict__ hn, ushort* __restrict__ hvT)
{
  const int t = threadIdx.x;
  const int r0 = blockIdx.x * 8;
  __shared__ float xs[8][F_IN];
  for (int i = t; i < 8 * F_IN; i += 128)
    xs[i >> 9][i & 511] = x[(size_t)(r0 + (i >> 9)) * F_IN + (i & 511)];
  __syncthreads();

  float acc0[8], acc1[8], acc2[8];
#pragma unroll
  for (int r = 0; r < 8; r++) { acc0[r] = 0.f; acc1[r] = 0.f; acc2[r] = 0.f; }

  for (int k = 0; k < F_IN; k++) {
    float wl = Wl[k * H_DIM + t];
    float wh = Wh[k * H_DIM + t];
    float wm = Wm[k * H_DIM + t];
#pragma unroll
    for (int r = 0; r < 8; r++) {
      float xv = xs[r][k];
      acc0[r] = fmaf(xv, wl, acc0[r]);
      acc1[r] = fmaf(xv, wh, acc1[r]);
      acc2[r] = fmaf(xv, wm, acc2[r]);
    }
  }

  __shared__ float red[24][2];
  const int wv = t >> 6;
  const int lane = t & 63;

#define REDUCE_BRANCH(ACC, B)                                        \
  _Pragma("unroll")                                                  \
  for (int r = 0; r < 8; r++) {                                      \
    float v = ACC[r] * ACC[r];                                       \
    v += __shfl_down(v, 32); v += __shfl_down(v, 16);                \
    v += __shfl_down(v, 8);  v += __shfl_down(v, 4);                 \
    v += __shfl_down(v, 2);  v += __shfl_down(v, 1);                 \
    if (lane == 0) red[(B) * 8 + r][wv] = v;                         \
  }
  REDUCE_BRANCH(acc0, 0)
  REDUCE_BRANCH(acc1, 1)
  REDUCE_BRANCH(acc2, 2)
  __syncthreads();

#define WRITE_BRANCH(ACC, B)                                                   \
  _Pragma("unroll")                                                            \
  for (int r = 0; r < 8; r++) {                                                \
    float nrm = sqrtf(red[(B) * 8 + r][0] + red[(B) * 8 + r][1]);              \
    float rn = 1.0f / fmaxf(nrm, EPSF);                                        \
    float h = ACC[r];                                                          \
    hn[((size_t)(B) * N_NODES + r0 + r) * H_DIM + t] = f2bf(h * rn);           \
    hvT[((size_t)(B) * H_DIM + t) * N_NODES + r0 + r] = f2bf(h);               \
  }
  WRITE_BRANCH(acc0, 0)
  WRITE_BRANCH(acc1, 1)
  WRITE_BRANCH(acc2, 2)
#undef REDUCE_BRANCH
#undef WRITE_BRANCH
}

// ---------------------------------------------------------------------------
// K2: flash attention layer 0, block-cooperative LDS staging (R8-proven)
//     + one-tile-ahead adj register prefetch (restored from R5).
//     4 waves/block, 64 q-rows/block; K-tile [32][128] and VT-tile [128][32]
//     staged (double-buffered) via global_load_lds with XOR-chunk-swizzled
//     sources; fragments read from LDS with matching swizzle (rule #21).
//     Softmax: p = (adj+eps)*exp2(s*log2e - SMAX).
// ---------------------------------------------------------------------------
__global__ __launch_bounds__(256) void flash0_kernel(
    const ushort* __restrict__ hn, const ushort* __restrict__ hvT,
    const float* __restrict__ adj_l, const float* __restrict__ adj_h,
    const float* __restrict__ adj_m,
    float* __restrict__ pl0, ushort* __restrict__ pO)
{
  const int tid = threadIdx.x;
  const int w = tid >> 6;
  const int lane = tid & 63;
  const int lr = lane & 15;
  const int lg = lane >> 4;
  const int ks = blockIdx.y;
  const int b = blockIdx.z;
  const int q0 = blockIdx.x * 64 + w * 16;
  const float* adj = (b == 0) ? adj_l : (b == 1) ? adj_h : adj_m;
  const ushort* Qg = hn + (size_t)b * N_NODES * H_DIM;
  const ushort* VTg = hvT + (size_t)b * H_DIM * N_NODES;
  const int kbase = ks * KLEN0;

  __shared__ ushort sK[2][32 * 128];   // [buf][k-row][d], chunk-swizzled
  __shared__ ushort sV[2][128 * 32];   // [buf][d-row][k], chunk-swizzled
  __shared__ ushort pbuf[4][16][40];

  // Q A-fragments (one-time global read)
  bf16x8 qf[4];
  {
    const ushort* qp = Qg + (size_t)(q0 + lr) * H_DIM + lg * 8;
#pragma unroll
    for (int u = 0; u < 4; u++) qf[u] = *(const bf16x8*)(qp + 32 * u);
  }

  f32x4 o[8];
#pragma unroll
  for (int dt = 0; dt < 8; dt++) o[dt] = (f32x4){0.f, 0.f, 0.f, 0.f};
  float lsum[4] = {0.f, 0.f, 0.f, 0.f};

  const int qrow_base = q0 + lg * 4;
  const float* ar[4];
#pragma unroll
  for (int r = 0; r < 4; r++)
    ar[r] = adj + (size_t)(qrow_base + r) * N_NODES + kbase;

  // --- staging slot decomposition (per-thread constants) ---
  const int sA = w * 128 + lane;
  const int sB = sA + 64;
  const int kkA = sA >> 4, kcA = sA & 15;
  const int kkB = sB >> 4, kcB = sB & 15;
  const size_t kOffA = (size_t)kkA * H_DIM + ((size_t)(kcA ^ (kkA & 7)) << 3);
  const size_t kOffB = (size_t)kkB * H_DIM + ((size_t)(kcB ^ (kkB & 7)) << 3);
  const int dA = sA >> 2, vcA = sA & 3;
  const int dB = sB >> 2, vcB = sB & 3;
  const size_t vOffA = (size_t)dA * N_NODES + ((size_t)(vcA ^ ((dA >> 1) & 3)) << 3);
  const size_t vOffB = (size_t)dB * N_NODES + ((size_t)(vcB ^ ((dB >> 1) & 3)) << 3);

#define STAGE(BUF, K0)                                                         \
  {                                                                            \
    const ushort* ksrc = Qg + (size_t)(K0) * H_DIM;                            \
    const ushort* vsrc = VTg + (K0);                                           \
    __builtin_amdgcn_global_load_lds(ksrc + kOffA,                             \
        (char*)&sK[BUF][0] + w * 2048, 16, 0, 0);                              \
    __builtin_amdgcn_global_load_lds(ksrc + kOffB,                             \
        (char*)&sK[BUF][0] + w * 2048 + 1024, 16, 0, 0);                       \
    __builtin_amdgcn_global_load_lds(vsrc + vOffA,                             \
        (char*)&sV[BUF][0] + w * 2048, 16, 0, 0);                              \
    __builtin_amdgcn_global_load_lds(vsrc + vOffB,                             \
        (char*)&sV[BUF][0] + w * 2048 + 1024, 16, 0, 0);                       \
  }

  STAGE(0, kbase)

  // adj register double-buffer: preload tile 0
  float a0c[4], a1c[4];
#pragma unroll
  for (int r = 0; r < 4; r++) { a0c[r] = ar[r][lr]; a1c[r] = ar[r][16 + lr]; }

  for (int t = 0; t < NT0; t++) {
    const int cur = t & 1;
    __syncthreads();   // staged tile t + prefetched adj[t] guaranteed resident
    if (t + 1 < NT0) STAGE(cur ^ 1, kbase + (t + 1) * 32)

    // issue next tile's adj loads now; consumed next iteration
    float a0n[4], a1n[4];
    if (t + 1 < NT0) {
#pragma unroll
      for (int r = 0; r < 4; r++) {
        a0n[r] = ar[r][(t + 1) * 32 + lr];
        a1n[r] = ar[r][(t + 1) * 32 + 16 + lr];
      }
    }

    // --- QK^T from LDS (swizzled reads) ---
    f32x4 s0 = (f32x4){0.f, 0.f, 0.f, 0.f};
    f32x4 s1 = (f32x4){0.f, 0.f, 0.f, 0.f};
    const char* sKc = (const char*)&sK[cur][0];
#pragma unroll
    for (int u = 0; u < 4; u++) {
      const int c0 = lg + 4 * u;
      bf16x8 kf0 = *(const bf16x8*)(sKc + lr * 256 + ((c0 ^ (lr & 7)) << 4));
      bf16x8 kf1 = *(const bf16x8*)(sKc + (lr + 16) * 256 + ((c0 ^ (lr & 7)) << 4));
      s0 = __builtin_amdgcn_mfma_f32_16x16x32_bf16(qf[u], kf0, s0, 0, 0, 0);
      s1 = __builtin_amdgcn_mfma_f32_16x16x32_bf16(qf[u], kf1, s1, 0, 0, 0);
    }
    // --- softmax numerator: p = (adj+eps) * exp2(s*log2e - SMAX) ---
    float p0[4], p1[4];
#pragma unroll
    for (int r = 0; r < 4; r++) {
      float e0 = exp2f(fmaf(s0[r], LOG2E, -SMAX));
      float e1 = exp2f(fmaf(s1[r], LOG2E, -SMAX));
      p0[r] = e0 * (a0c[r] + EPSF);
      p1[r] = e1 * (a1c[r] + EPSF);
      lsum[r] += p0[r] + p1[r];
    }
    // --- P -> per-wave LDS (C/D -> A-frag round trip) ---
#pragma unroll
    for (int r = 0; r < 4; r++) {
      pbuf[w][lg * 4 + r][lr]      = f2bf(p0[r]);
      pbuf[w][lg * 4 + r][16 + lr] = f2bf(p1[r]);
    }
    bf16x8 pf = *(const bf16x8*)&pbuf[w][lr][lg * 8];
    // --- PV from LDS (swizzled reads) ---
    const char* sVc = (const char*)&sV[cur][0];
#pragma unroll
    for (int dt = 0; dt < 8; dt++) {
      const int d = dt * 16 + lr;
      bf16x8 vf = *(const bf16x8*)(sVc + d * 64 + ((lg ^ ((d >> 1) & 3)) << 4));
      o[dt] = __builtin_amdgcn_mfma_f32_16x16x32_bf16(pf, vf, o[dt], 0, 0, 0);
    }
    // rotate adj buffer
#pragma unroll
    for (int r = 0; r < 4; r++) { a0c[r] = a0n[r]; a1c[r] = a1n[r]; }
  }
#undef STAGE

  const int ps = b * NKS0 + ks;
#pragma unroll
  for (int r = 0; r < 4; r++) {
    const size_t row = (size_t)ps * N_NODES + qrow_base + r;
    float psum = lsum[r];
#pragma unroll
    for (int d = 1; d < 16; d <<= 1) psum += __shfl_xor(psum, d);
    if (lr == 0) pl0[row] = psum;
#pragma unroll
    for (int dt = 0; dt < 8; dt++)
      pO[row * H_DIM + dt * 16 + lr] = f2bf(o[dt][r]);
  }
}

// ---------------------------------------------------------------------------
// K2b: merge the NKS0 K-split partials (plain sums; static max) -> o0
// ---------------------------------------------------------------------------
__global__ __launch_bounds__(128) void combine0_kernel(
    const float* __restrict__ pl0, const ushort* __restrict__ pO,
    float* __restrict__ o0)
{
  const int q = blockIdx.x;
  const int b = blockIdx.y;
  const int t = threadIdx.x;
  float L = 0.f, O = 0.f;
#pragma unroll
  for (int ks = 0; ks < NKS0; ks++) {
    const size_t row = (size_t)(b * NKS0 + ks) * N_NODES + q;
    L += pl0[row];
    O += bf2f(pO[row * H_DIM + t]);
  }
  o0[((size_t)b * N_NODES + q) * H_DIM + t] = O / L;
}

// ---------------------------------------------------------------------------
// K3: h_comb = sum_b softmax(g0)_b * relu(o0_b + b0_b); hb = h_comb @ W1 (x3);
//     row norms -> hn1b (bf16 [3][4096][16]); hbT (bf16 [3][16][4096]).
// ---------------------------------------------------------------------------
__global__ __launch_bounds__(128) void mix1_kernel(
    const float* __restrict__ o0,
    const float* __restrict__ bl0, const float* __restrict__ bh0,
    const float* __restrict__ bm0,
    const float* __restrict__ Wl1, const float* __restrict__ Wh1,
    const float* __restrict__ Wm1,
    const float* __restrict__ g0,
    ushort* __restrict__ hn1b, ushort* __restrict__ hbT)
{
  const int q = blockIdx.x;
  const int t = threadIdx.x;
  float ga = g0[0], gb = g0[1], gc = g0[2];
  float gm = fmaxf(ga, fmaxf(gb, gc));
  float e0 = expf(ga - gm), e1 = expf(gb - gm), e2 = expf(gc - gm);
  float ei = 1.0f / (e0 + e1 + e2);
  const size_t ND = (size_t)N_NODES * H_DIM;

  __shared__ float hc[H_DIM];
  float v = e0 * ei * fmaxf(o0[(size_t)q * H_DIM + t] + bl0[t], 0.f)
          + e1 * ei * fmaxf(o0[ND + (size_t)q * H_DIM + t] + bh0[t], 0.f)
          + e2 * ei * fmaxf(o0[2 * ND + (size_t)q * H_DIM + t] + bm0[t], 0.f);
  hc[t] = v;
  __syncthreads();

  __shared__ float shb[48];
  if (t < 48) {
    const int b = t >> 4, j = t & 15;
    const float* W = (b == 0) ? Wl1 : (b == 1) ? Wh1 : Wm1;
    float s = 0.f;
    for (int k = 0; k < H_DIM; k++) s = fmaf(hc[k], W[k * C_DIM + j], s);
    shb[t] = s;
  }
  __syncthreads();
  __shared__ float rns[3];
  if (t < 3) {
    float s = 0.f;
#pragma unroll
    for (int j = 0; j < C_DIM; j++) { float u = shb[t * C_DIM + j]; s = fmaf(u, u, s); }
    rns[t] = 1.0f / fmaxf(sqrtf(s), EPSF);
  }
  __syncthreads();
  if (t < 48) {
    const int b = t >> 4, j = t & 15;
    hbT[((size_t)b * C_DIM + j) * N_NODES + q] = f2bf(shb[t]);
    hn1b[((size_t)b * N_NODES + q) * C_DIM + j] = f2bf(shb[t] * rns[b]);
  }
}

// ---------------------------------------------------------------------------
// K4: flash attention layer 1, D=16, MFMA 16x16x16, swapped QK^T, K-split 8.
//     4 independent waves/block; wave = 16 q-rows x 512 K-cols.
//     adj prefetched one tile ahead; numerator via (adj+eps)*exp2(...).
// ---------------------------------------------------------------------------
__global__ __launch_bounds__(256) void flash1_kernel(
    const ushort* __restrict__ hn1b, const ushort* __restrict__ hbT,
    const float* __restrict__ adj_l, const float* __restrict__ adj_h,
    const float* __restrict__ adj_m,
    float* __restrict__ pl, float* __restrict__ pacc)
{
  const int tid = threadIdx.x;
  const int wid = tid >> 6;
  const int lane = tid & 63;
  const int lr = lane & 15;
  const int lg = lane >> 4;
  const int q0 = (blockIdx.x * 4 + wid) * 16;
  const int ks = blockIdx.y;
  const int b = blockIdx.z;
  const float* adj = (b == 0) ? adj_l : (b == 1) ? adj_h : adj_m;
  const ushort* Qn = hn1b + (size_t)b * N_NODES * C_DIM;
  const ushort* VT = hbT + (size_t)b * C_DIM * N_NODES;
  const int kbase = ks * (N_NODES / NKS1);
  const int nt = (N_NODES / NKS1) / 32;

  const bf16x4 qf = *(const bf16x4*)(Qn + (size_t)(q0 + lr) * C_DIM + lg * 4);
  const f32x4 zero = (f32x4){0.f, 0.f, 0.f, 0.f};
  f32x4 o = zero;
  float lsum = 0.f;
  const float* arow = adj + (size_t)(q0 + lr) * N_NODES;
  const ushort* vrow = VT + (size_t)lr * N_NODES;

  f32x4 a0c = *(const f32x4*)(arow + kbase + lg * 4);
  f32x4 a1c = *(const f32x4*)(arow + kbase + 16 + lg * 4);

  for (int t = 0; t < nt; t++) {
    const int k0 = kbase + t * 32;
    f32x4 a0n, a1n;
    if (t + 1 < nt) {
      a0n = *(const f32x4*)(arow + k0 + 32 + lg * 4);
      a1n = *(const f32x4*)(arow + k0 + 48 + lg * 4);
    }
    bf16x4 kf0 = *(const bf16x4*)(Qn + (size_t)(k0 + lr) * C_DIM + lg * 4);
    bf16x4 kf1 = *(const bf16x4*)(Qn + (size_t)(k0 + 16 + lr) * C_DIM + lg * 4);
    f32x4 s0 = __builtin_amdgcn_mfma_f32_16x16x16bf16_1k(kf0, qf, zero, 0, 0, 0);
    f32x4 s1 = __builtin_amdgcn_mfma_f32_16x16x16bf16_1k(kf1, qf, zero, 0, 0, 0);
    bf16x4 pf0, pf1;
#pragma unroll
    for (int r = 0; r < 4; r++) {
      float e0 = exp2f(fmaf(s0[r], LOG2E, -SMAX));
      float e1 = exp2f(fmaf(s1[r], LOG2E, -SMAX));
      float p0 = e0 * (a0c[r] + EPSF);
      float p1 = e1 * (a1c[r] + EPSF);
      lsum += p0 + p1;
      pf0[r] = (short)f2bf(p0);
      pf1[r] = (short)f2bf(p1);
    }
    bf16x4 vf0 = *(const bf16x4*)(vrow + k0 + lg * 4);
    bf16x4 vf1 = *(const bf16x4*)(vrow + k0 + 16 + lg * 4);
    o = __builtin_amdgcn_mfma_f32_16x16x16bf16_1k(pf0, vf0, o, 0, 0, 0);
    o = __builtin_amdgcn_mfma_f32_16x16x16bf16_1k(pf1, vf1, o, 0, 0, 0);
    a0c = a0n; a1c = a1n;
  }

  const int ps = b * NKS1 + ks;
  float psum = lsum;
  psum += __shfl_xor(psum, 16);
  psum += __shfl_xor(psum, 32);
  if (lg == 0) pl[(size_t)ps * N_NODES + q0 + lr] = psum;
#pragma unroll
  for (int r = 0; r < 4; r++)
    pacc[((size_t)ps * N_NODES + q0 + lg * 4 + r) * C_DIM + lr] = o[r];
}

// ---------------------------------------------------------------------------
// K5: merge the NKS1 K-split partials per (branch, row) — plain sums.
// ---------------------------------------------------------------------------
__global__ __launch_bounds__(256) void combine1_kernel(
    const float* __restrict__ pl, const float* __restrict__ pacc,
    float* __restrict__ o1)
{
  const int q = blockIdx.x * 256 + threadIdx.x;
  const int b = blockIdx.y;
  float L = 0.f;
  f32x4 out0 = (f32x4){0,0,0,0}, out1 = (f32x4){0,0,0,0},
        out2 = (f32x4){0,0,0,0}, out3 = (f32x4){0,0,0,0};
#pragma unroll
  for (int ks = 0; ks < NKS1; ks++) {
    const size_t pidx = (size_t)(b * NKS1 + ks) * N_NODES + q;
    L += pl[pidx];
    const f32x4* pa = (const f32x4*)(pacc + pidx * C_DIM);
    out0 += pa[0]; out1 += pa[1]; out2 += pa[2]; out3 += pa[3];
  }
  float invL = 1.0f / L;
  f32x4* dst = (f32x4*)(o1 + ((size_t)b * N_NODES + q) * C_DIM);
  dst[0] = out0 * invL; dst[1] = out1 * invL; dst[2] = out2 * invL; dst[3] = out3 * invL;
}

// ---------------------------------------------------------------------------
// K6: add biases, softmax(g1)-weighted branch mix, log_softmax over 16.
// ---------------------------------------------------------------------------
__global__ __launch_bounds__(256) void final_kernel(
    const float* __restrict__ o1,
    const float* __restrict__ bl1, const float* __restrict__ bh1,
    const float* __restrict__ bm1,
    const float* __restrict__ g1, float* __restrict__ out)
{
  const int q = blockIdx.x * 256 + threadIdx.x;
  float ga = g1[0], gb = g1[1], gc = g1[2];
  float gm = fmaxf(ga, fmaxf(gb, gc));
  float e0 = expf(ga - gm), e1 = expf(gb - gm), e2 = expf(gc - gm);
  float ei = 1.0f / (e0 + e1 + e2);
  float w0 = e0 * ei, w1 = e1 * ei, w2 = e2 * ei;
  const size_t NC = (size_t)N_NODES * C_DIM;

  float v[16];
#pragma unroll
  for (int i = 0; i < 4; i++) {
    f32x4 a = ((const f32x4*)(o1 + (size_t)q * C_DIM))[i];
    f32x4 bA = ((const f32x4*)(o1 + NC + (size_t)q * C_DIM))[i];
    f32x4 c = ((const f32x4*)(o1 + 2 * NC + (size_t)q * C_DIM))[i];
    f32x4 xl = ((const f32x4*)bl1)[i];
    f32x4 xh = ((const f32x4*)bh1)[i];
    f32x4 xm = ((const f32x4*)bm1)[i];
#pragma unroll
    for (int j = 0; j < 4; j++)
      v[i * 4 + j] = w0 * (a[j] + xl[j]) + w1 * (bA[j] + xh[j]) + w2 * (c[j] + xm[j]);
  }
  float mx = -1e30f;
#pragma unroll
  for (int j = 0; j < 16; j++) mx = fmaxf(mx, v[j]);
  float se = 0.f;
#pragma unroll
  for (int j = 0; j < 16; j++) se += expf(v[j] - mx);
  float lse = mx + logf(se);
  f32x4* dst = (f32x4*)(out + (size_t)q * C_DIM);
#pragma unroll
  for (int i = 0; i < 4; i++) {
    f32x4 r;
#pragma unroll
    for (int j = 0; j < 4; j++) r[j] = v[i * 4 + j] - lse;
    dst[i] = r;
  }
}

// ---------------------------------------------------------------------------
extern "C" void kernel_launch(void* const* d_in, const int* in_sizes, int n_in,
                              void* d_out, int out_size, void* d_ws, size_t ws_size,
                              hipStream_t stream) {
  (void)in_sizes; (void)n_in; (void)out_size; (void)ws_size;
  const float* x     = (const float*)d_in[0];
  const float* adj_l = (const float*)d_in[1];
  const float* adj_h = (const float*)d_in[2];
  const float* adj_m = (const float*)d_in[3];
  const float* w_l0  = (const float*)d_in[4];
  const float* b_l0  = (const float*)d_in[5];
  const float* w_h0  = (const float*)d_in[6];
  const float* b_h0  = (const float*)d_in[7];
  const float* w_m0  = (const float*)d_in[8];
  const float* b_m0  = (const float*)d_in[9];
  const float* w_l1  = (const float*)d_in[10];
  const float* b_l1  = (const float*)d_in[11];
  const float* w_h1  = (const float*)d_in[12];
  const float* b_h1  = (const float*)d_in[13];
  const float* w_m1  = (const float*)d_in[14];
  const float* b_m1  = (const float*)d_in[15];
  const float* g0    = (const float*)d_in[16];
  const float* g1    = (const float*)d_in[17];
  float* out = (float*)d_out;

  char* ws = (char*)d_ws;
  // persistent across phases:
  ushort* hn  = (ushort*)(ws);                  // [0, 3MB)
  ushort* hvT = (ushort*)(ws + (3u << 20));     // [3MB, 6MB)
  float*  o0  = (float*)(ws + (6u << 20));      // [6MB, 12MB)
  // phase A (layer-0 partials, dead after combine0): peak 36.5MB (<37.7 proven)
  float*  pl0 = (float*)(ws + (12u << 20));                    // 384KB
  ushort* pO  = (ushort*)(ws + (12u << 20) + (512u << 10));    // 24MB (bf16)
  // phase B (layer-1 scratch), reuses phase-A region:
  ushort* hn1b= (ushort*)(ws + (12u << 20));                   // 384KB
  ushort* hbT = (ushort*)(ws + (12u << 20) + (512u << 10));    // 384KB
  float*  pl  = (float*)(ws + (13u << 20));                    // 384KB
  float*  pacc= (float*)(ws + (13u << 20) + (512u << 10));     // 6MB
  float*  o1  = (float*)(ws + (20u << 20));                    // 768KB

  proj0_kernel<<<dim3(512), dim3(128), 0, stream>>>(x, w_l0, w_h0, w_m0, hn, hvT);
  flash0_kernel<<<dim3(64, NKS0, 3), dim3(256), 0, stream>>>(hn, hvT, adj_l, adj_h, adj_m,
                                                             pl0, pO);
  combine0_kernel<<<dim3(4096, 3), dim3(128), 0, stream>>>(pl0, pO, o0);
  mix1_kernel<<<dim3(4096), dim3(128), 0, stream>>>(o0, b_l0, b_h0, b_m0,
                                                    w_l1, w_h1, w_m1, g0, hn1b, hbT);
  flash1_kernel<<<dim3(64, NKS1, 3), dim3(256), 0, stream>>>(hn1b, hbT, adj_l, adj_h, adj_m,
                                                             pl, pacc);
  combine1_kernel<<<dim3(16, 3), dim3(256), 0, stream>>>(pl, pacc, o1);
  final_kernel<<<dim3(16), dim3(256), 0, stream>>>(o1, b_l1, b_h1, b_m1, g1, out);
}

// Round 11
// 160.466 us; speedup vs baseline: 1.2912x; 1.2912x over previous
//
#include <hip/hip_runtime.h>

#define N_NODES 4096
#define F_IN 512
#define H_DIM 128
#define C_DIM 16
#define EPSF 1e-8f
#define LOG2E 1.4426950408889634f
#define SMAX 2.0f   // static softmax max: logits = cos/tau*log2e + log2(adj+eps) < 2 always
#define NKS0 8      // layer-0 K-splits
#define KLEN0 (N_NODES / NKS0)
#define NT0 (KLEN0 / 32)
#define NKS1 8      // layer-1 K-splits

typedef __attribute__((ext_vector_type(8))) short bf16x8;
typedef __attribute__((ext_vector_type(4))) short bf16x4;
typedef __attribute__((ext_vector_type(4))) float f32x4;

__device__ __forceinline__ ushort f2bf(float f){
  union { float f; unsigned u; } v; v.f = f;
  unsigned u = v.u;
  return (ushort)((u + 0x7fffu + ((u >> 16) & 1u)) >> 16);
}
__device__ __forceinline__ float bf2f(ushort h){
  union { unsigned u; float f; } v; v.u = ((unsigned)h) << 16;
  return v.f;
}

// ---------------------------------------------------------------------------
// K1: h = x @ W0 for 3 branches, k-split x2 within block (256 thr, 4 waves);
//     row norms; write hn (bf16, row-major) and hvT (bf16 [3][128][4096]).
// ---------------------------------------------------------------------------
__global__ __launch_bounds__(256) void proj0_kernel(
    const float* __restrict__ x,
    const float* __restrict__ Wl, const float* __restrict__ Wh,
    const float* __restrict__ Wm,
    ushort* __restrict__ hn, ushort* __restrict__ hvT)
{
  const int t = threadIdx.x;
  const int d = t & 127;
  const int half = t >> 7;
  const int r0 = blockIdx.x * 8;
  __shared__ float xs[8][F_IN];
  for (int i = t; i < 8 * F_IN; i += 256)
    xs[i >> 9][i & 511] = x[(size_t)(r0 + (i >> 9)) * F_IN + (i & 511)];
  __syncthreads();

  float acc0[8], acc1[8], acc2[8];
#pragma unroll
  for (int r = 0; r < 8; r++) { acc0[r] = 0.f; acc1[r] = 0.f; acc2[r] = 0.f; }

  const int k0 = half * (F_IN / 2);
  for (int k = k0; k < k0 + F_IN / 2; k++) {
    float wl = Wl[k * H_DIM + d];
    float wh = Wh[k * H_DIM + d];
    float wm = Wm[k * H_DIM + d];
#pragma unroll
    for (int r = 0; r < 8; r++) {
      float xv = xs[r][k];
      acc0[r] = fmaf(xv, wl, acc0[r]);
      acc1[r] = fmaf(xv, wh, acc1[r]);
      acc2[r] = fmaf(xv, wm, acc2[r]);
    }
  }

  // cross-half combine
  __shared__ float part[3][8][128];
  if (half == 1) {
#pragma unroll
    for (int r = 0; r < 8; r++) {
      part[0][r][d] = acc0[r]; part[1][r][d] = acc1[r]; part[2][r][d] = acc2[r];
    }
  }
  __syncthreads();
  if (half == 0) {
#pragma unroll
    for (int r = 0; r < 8; r++) {
      acc0[r] += part[0][r][d]; acc1[r] += part[1][r][d]; acc2[r] += part[2][r][d];
    }
  }

  __shared__ float red[24][2];
  const int wv = t >> 6;        // 0..1 for half==0
  const int lane = t & 63;

#define REDUCE_BRANCH(ACC, B)                                        \
  _Pragma("unroll")                                                  \
  for (int r = 0; r < 8; r++) {                                      \
    float v = ACC[r] * ACC[r];                                       \
    v += __shfl_down(v, 32); v += __shfl_down(v, 16);                \
    v += __shfl_down(v, 8);  v += __shfl_down(v, 4);                 \
    v += __shfl_down(v, 2);  v += __shfl_down(v, 1);                 \
    if (lane == 0) red[(B) * 8 + r][wv] = v;                         \
  }
  if (half == 0) {
    REDUCE_BRANCH(acc0, 0)
    REDUCE_BRANCH(acc1, 1)
    REDUCE_BRANCH(acc2, 2)
  }
  __syncthreads();

#define WRITE_BRANCH(ACC, B)                                                   \
  _Pragma("unroll")                                                            \
  for (int r = 0; r < 8; r++) {                                                \
    float nrm = sqrtf(red[(B) * 8 + r][0] + red[(B) * 8 + r][1]);              \
    float rn = 1.0f / fmaxf(nrm, EPSF);                                        \
    float h = ACC[r];                                                          \
    hn[((size_t)(B) * N_NODES + r0 + r) * H_DIM + d] = f2bf(h * rn);           \
    hvT[((size_t)(B) * H_DIM + d) * N_NODES + r0 + r] = f2bf(h);               \
  }
  if (half == 0) {
    WRITE_BRANCH(acc0, 0)
    WRITE_BRANCH(acc1, 1)
    WRITE_BRANCH(acc2, 2)
  }
#undef REDUCE_BRANCH
#undef WRITE_BRANCH
}

// ---------------------------------------------------------------------------
// K2: flash attention layer 0, block-cooperative LDS staging, 8 waves/block
//     (512 thr, 128 q-rows): one 16KB K/V stage feeds 8 waves, 24 waves/CU.
//     Double-buffered, XOR-chunk-swizzled source + matching swizzled reads.
//     Softmax: p = (adj+eps)*exp2(s*log2e - SMAX).
// ---------------------------------------------------------------------------
__global__ __launch_bounds__(512) void flash0_kernel(
    const ushort* __restrict__ hn, const ushort* __restrict__ hvT,
    const float* __restrict__ adj_l, const float* __restrict__ adj_h,
    const float* __restrict__ adj_m,
    float* __restrict__ pl0, ushort* __restrict__ pO)
{
  const int tid = threadIdx.x;
  const int w = tid >> 6;        // 0..7
  const int lane = tid & 63;
  const int lr = lane & 15;
  const int lg = lane >> 4;
  const int ks = blockIdx.y;
  const int b = blockIdx.z;
  const int q0 = blockIdx.x * 128 + w * 16;
  const float* adj = (b == 0) ? adj_l : (b == 1) ? adj_h : adj_m;
  const ushort* Qg = hn + (size_t)b * N_NODES * H_DIM;
  const ushort* VTg = hvT + (size_t)b * H_DIM * N_NODES;
  const int kbase = ks * KLEN0;

  __shared__ ushort sK[2][32 * 128];   // [buf][k-row][d], chunk-swizzled
  __shared__ ushort sV[2][128 * 32];   // [buf][d-row][k], chunk-swizzled
  __shared__ ushort pbuf[8][16][40];

  bf16x8 qf[4];
  {
    const ushort* qp = Qg + (size_t)(q0 + lr) * H_DIM + lg * 8;
#pragma unroll
    for (int u = 0; u < 4; u++) qf[u] = *(const bf16x8*)(qp + 32 * u);
  }

  f32x4 o[8];
#pragma unroll
  for (int dt = 0; dt < 8; dt++) o[dt] = (f32x4){0.f, 0.f, 0.f, 0.f};
  float lsum[4] = {0.f, 0.f, 0.f, 0.f};

  const int qrow_base = q0 + lg * 4;
  const float* ar[4];
#pragma unroll
  for (int r = 0; r < 4; r++)
    ar[r] = adj + (size_t)(qrow_base + r) * N_NODES + kbase;

  // staging: one K slot + one V slot per thread (512 slots each)
  const int kk = tid >> 4, kc = tid & 15;
  const size_t kOff = (size_t)kk * H_DIM + ((size_t)(kc ^ (kk & 7)) << 3);
  const int dV = tid >> 2, vc = tid & 3;
  const size_t vOff = (size_t)dV * N_NODES + ((size_t)(vc ^ ((dV >> 1) & 3)) << 3);

#define STAGE(BUF, K0)                                                         \
  {                                                                            \
    const ushort* ksrc = Qg + (size_t)(K0) * H_DIM;                            \
    const ushort* vsrc = VTg + (K0);                                           \
    __builtin_amdgcn_global_load_lds(ksrc + kOff,                              \
        (char*)&sK[BUF][0] + w * 1024, 16, 0, 0);                              \
    __builtin_amdgcn_global_load_lds(vsrc + vOff,                              \
        (char*)&sV[BUF][0] + w * 1024, 16, 0, 0);                              \
  }

  STAGE(0, kbase)

  float a0c[4], a1c[4];
#pragma unroll
  for (int r = 0; r < 4; r++) { a0c[r] = ar[r][lr]; a1c[r] = ar[r][16 + lr]; }

  for (int t = 0; t < NT0; t++) {
    const int cur = t & 1;
    __syncthreads();   // staged tile t + adj[t] resident
    if (t + 1 < NT0) STAGE(cur ^ 1, kbase + (t + 1) * 32)

    float a0n[4], a1n[4];
    if (t + 1 < NT0) {
#pragma unroll
      for (int r = 0; r < 4; r++) {
        a0n[r] = ar[r][(t + 1) * 32 + lr];
        a1n[r] = ar[r][(t + 1) * 32 + 16 + lr];
      }
    }

    // --- QK^T from LDS (swizzled reads) ---
    f32x4 s0 = (f32x4){0.f, 0.f, 0.f, 0.f};
    f32x4 s1 = (f32x4){0.f, 0.f, 0.f, 0.f};
    const char* sKc = (const char*)&sK[cur][0];
#pragma unroll
    for (int u = 0; u < 4; u++) {
      const int c0 = lg + 4 * u;
      bf16x8 kf0 = *(const bf16x8*)(sKc + lr * 256 + ((c0 ^ (lr & 7)) << 4));
      bf16x8 kf1 = *(const bf16x8*)(sKc + (lr + 16) * 256 + ((c0 ^ (lr & 7)) << 4));
      s0 = __builtin_amdgcn_mfma_f32_16x16x32_bf16(qf[u], kf0, s0, 0, 0, 0);
      s1 = __builtin_amdgcn_mfma_f32_16x16x32_bf16(qf[u], kf1, s1, 0, 0, 0);
    }
    // --- softmax numerator ---
    float p0[4], p1[4];
#pragma unroll
    for (int r = 0; r < 4; r++) {
      float e0 = exp2f(fmaf(s0[r], LOG2E, -SMAX));
      float e1 = exp2f(fmaf(s1[r], LOG2E, -SMAX));
      p0[r] = e0 * (a0c[r] + EPSF);
      p1[r] = e1 * (a1c[r] + EPSF);
      lsum[r] += p0[r] + p1[r];
    }
    // --- P -> per-wave LDS round trip ---
#pragma unroll
    for (int r = 0; r < 4; r++) {
      pbuf[w][lg * 4 + r][lr]      = f2bf(p0[r]);
      pbuf[w][lg * 4 + r][16 + lr] = f2bf(p1[r]);
    }
    bf16x8 pf = *(const bf16x8*)&pbuf[w][lr][lg * 8];
    // --- PV from LDS (swizzled reads) ---
    const char* sVc = (const char*)&sV[cur][0];
#pragma unroll
    for (int dt = 0; dt < 8; dt++) {
      const int dd = dt * 16 + lr;
      bf16x8 vf = *(const bf16x8*)(sVc + dd * 64 + ((lg ^ ((dd >> 1) & 3)) << 4));
      o[dt] = __builtin_amdgcn_mfma_f32_16x16x32_bf16(pf, vf, o[dt], 0, 0, 0);
    }
#pragma unroll
    for (int r = 0; r < 4; r++) { a0c[r] = a0n[r]; a1c[r] = a1n[r]; }
  }
#undef STAGE

  const int ps = b * NKS0 + ks;
#pragma unroll
  for (int r = 0; r < 4; r++) {
    const size_t row = (size_t)ps * N_NODES + qrow_base + r;
    float psum = lsum[r];
#pragma unroll
    for (int dd = 1; dd < 16; dd <<= 1) psum += __shfl_xor(psum, dd);
    if (lr == 0) pl0[row] = psum;
#pragma unroll
    for (int dt = 0; dt < 8; dt++)
      pO[row * H_DIM + dt * 16 + lr] = f2bf(o[dt][r]);
  }
}

// ---------------------------------------------------------------------------
// K3: fused combine0+mix1: merge K-split partials, branch mix + relu, @W1,
//     row norms -> hn1b (bf16 [3][4096][16]); hbT (bf16 [3][16][4096]).
// ---------------------------------------------------------------------------
__global__ __launch_bounds__(128) void mix1_kernel(
    const float* __restrict__ pl0, const ushort* __restrict__ pO,
    const float* __restrict__ bl0, const float* __restrict__ bh0,
    const float* __restrict__ bm0,
    const float* __restrict__ Wl1, const float* __restrict__ Wh1,
    const float* __restrict__ Wm1,
    const float* __restrict__ g0,
    ushort* __restrict__ hn1b, ushort* __restrict__ hbT)
{
  const int q = blockIdx.x;
  const int t = threadIdx.x;
  float ga = g0[0], gb = g0[1], gc = g0[2];
  float gm = fmaxf(ga, fmaxf(gb, gc));
  float e0 = expf(ga - gm), e1 = expf(gb - gm), e2 = expf(gc - gm);
  float ei = 1.0f / (e0 + e1 + e2);

  __shared__ float Ls[3];
  if (t < 3) {
    float L = 0.f;
#pragma unroll
    for (int ks = 0; ks < NKS0; ks++) L += pl0[(size_t)(t * NKS0 + ks) * N_NODES + q];
    Ls[t] = L;
  }
  float O0 = 0.f, O1 = 0.f, O2 = 0.f;
#pragma unroll
  for (int ks = 0; ks < NKS0; ks++) {
    O0 += bf2f(pO[((size_t)(0 * NKS0 + ks) * N_NODES + q) * H_DIM + t]);
    O1 += bf2f(pO[((size_t)(1 * NKS0 + ks) * N_NODES + q) * H_DIM + t]);
    O2 += bf2f(pO[((size_t)(2 * NKS0 + ks) * N_NODES + q) * H_DIM + t]);
  }
  __syncthreads();

  __shared__ float hc[H_DIM];
  hc[t] = e0 * ei * fmaxf(O0 / Ls[0] + bl0[t], 0.f)
        + e1 * ei * fmaxf(O1 / Ls[1] + bh0[t], 0.f)
        + e2 * ei * fmaxf(O2 / Ls[2] + bm0[t], 0.f);
  __syncthreads();

  __shared__ float shb[48];
  if (t < 48) {
    const int b = t >> 4, j = t & 15;
    const float* W = (b == 0) ? Wl1 : (b == 1) ? Wh1 : Wm1;
    float s = 0.f;
    for (int k = 0; k < H_DIM; k++) s = fmaf(hc[k], W[k * C_DIM + j], s);
    shb[t] = s;
  }
  __syncthreads();
  __shared__ float rns[3];
  if (t < 3) {
    float s = 0.f;
#pragma unroll
    for (int j = 0; j < C_DIM; j++) { float u = shb[t * C_DIM + j]; s = fmaf(u, u, s); }
    rns[t] = 1.0f / fmaxf(sqrtf(s), EPSF);
  }
  __syncthreads();
  if (t < 48) {
    const int b = t >> 4, j = t & 15;
    hbT[((size_t)b * C_DIM + j) * N_NODES + q] = f2bf(shb[t]);
    hn1b[((size_t)b * N_NODES + q) * C_DIM + j] = f2bf(shb[t] * rns[b]);
  }
}

// ---------------------------------------------------------------------------
// K4: flash attention layer 1, D=16, MFMA 16x16x16, swapped QK^T, K-split 8.
//     adj staged in LDS [64 q-rows][32 k] double-buffered via global_load_lds
//     (XOR-chunk swizzle both sides); Q/K/V direct (L2-resident).
// ---------------------------------------------------------------------------
__global__ __launch_bounds__(256) void flash1_kernel(
    const ushort* __restrict__ hn1b, const ushort* __restrict__ hbT,
    const float* __restrict__ adj_l, const float* __restrict__ adj_h,
    const float* __restrict__ adj_m,
    float* __restrict__ pl, float* __restrict__ pacc)
{
  const int tid = threadIdx.x;
  const int wid = tid >> 6;
  const int lane = tid & 63;
  const int lr = lane & 15;
  const int lg = lane >> 4;
  const int qblk = blockIdx.x * 64;
  const int q0 = qblk + wid * 16;
  const int ks = blockIdx.y;
  const int b = blockIdx.z;
  const float* adj = (b == 0) ? adj_l : (b == 1) ? adj_h : adj_m;
  const ushort* Qn = hn1b + (size_t)b * N_NODES * C_DIM;
  const ushort* VT = hbT + (size_t)b * C_DIM * N_NODES;
  const int kbase = ks * (N_NODES / NKS1);
  const int nt = (N_NODES / NKS1) / 32;

  __shared__ float sAdj[2][64 * 32];   // [buf][row][col], chunk-swizzled

  const bf16x4 qf = *(const bf16x4*)(Qn + (size_t)(q0 + lr) * C_DIM + lg * 4);
  const f32x4 zero = (f32x4){0.f, 0.f, 0.f, 0.f};
  f32x4 o = zero;
  float lsum = 0.f;
  const ushort* vrow = VT + (size_t)lr * N_NODES;

  // staging slots: sA=tid, sB=tid+256 (512 slots of 16B = 8KB)
  const int rowA = tid >> 3, cA = tid & 7;
  const int rowB = rowA + 32;
  const size_t aOffA = (size_t)rowA * N_NODES + ((size_t)(cA ^ (rowA & 7)) << 2);
  const size_t aOffB = (size_t)rowB * N_NODES + ((size_t)(cA ^ (rowB & 7)) << 2);
  const float* adjq = adj + (size_t)qblk * N_NODES;

#define STAGE1(BUF, K0)                                                        \
  {                                                                            \
    const float* asrc = adjq + (K0);                                           \
    __builtin_amdgcn_global_load_lds(asrc + aOffA,                             \
        (char*)&sAdj[BUF][0] + wid * 1024, 16, 0, 0);                          \
    __builtin_amdgcn_global_load_lds(asrc + aOffB,                             \
        (char*)&sAdj[BUF][0] + 4096 + wid * 1024, 16, 0, 0);                   \
  }

  STAGE1(0, kbase)

  const int rowL = wid * 16 + lr;
  const int adr0 = rowL * 32 + ((lg ^ (rowL & 7)) << 2);
  const int adr1 = rowL * 32 + (((4 + lg) ^ (rowL & 7)) << 2);

  for (int t = 0; t < nt; t++) {
    const int cur = t & 1;
    __syncthreads();
    if (t + 1 < nt) STAGE1(cur ^ 1, kbase + (t + 1) * 32)

    const int k0 = kbase + t * 32;
    bf16x4 kf0 = *(const bf16x4*)(Qn + (size_t)(k0 + lr) * C_DIM + lg * 4);
    bf16x4 kf1 = *(const bf16x4*)(Qn + (size_t)(k0 + 16 + lr) * C_DIM + lg * 4);
    f32x4 s0 = __builtin_amdgcn_mfma_f32_16x16x16bf16_1k(kf0, qf, zero, 0, 0, 0);
    f32x4 s1 = __builtin_amdgcn_mfma_f32_16x16x16bf16_1k(kf1, qf, zero, 0, 0, 0);
    f32x4 a0 = *(const f32x4*)&sAdj[cur][adr0];
    f32x4 a1 = *(const f32x4*)&sAdj[cur][adr1];
    bf16x4 pf0, pf1;
#pragma unroll
    for (int r = 0; r < 4; r++) {
      float e0 = exp2f(fmaf(s0[r], LOG2E, -SMAX));
      float e1 = exp2f(fmaf(s1[r], LOG2E, -SMAX));
      float p0 = e0 * (a0[r] + EPSF);
      float p1 = e1 * (a1[r] + EPSF);
      lsum += p0 + p1;
      pf0[r] = (short)f2bf(p0);
      pf1[r] = (short)f2bf(p1);
    }
    bf16x4 vf0 = *(const bf16x4*)(vrow + k0 + lg * 4);
    bf16x4 vf1 = *(const bf16x4*)(vrow + k0 + 16 + lg * 4);
    o = __builtin_amdgcn_mfma_f32_16x16x16bf16_1k(pf0, vf0, o, 0, 0, 0);
    o = __builtin_amdgcn_mfma_f32_16x16x16bf16_1k(pf1, vf1, o, 0, 0, 0);
  }
#undef STAGE1

  const int ps = b * NKS1 + ks;
  float psum = lsum;
  psum += __shfl_xor(psum, 16);
  psum += __shfl_xor(psum, 32);
  if (lg == 0) pl[(size_t)ps * N_NODES + q0 + lr] = psum;
#pragma unroll
  for (int r = 0; r < 4; r++)
    pacc[((size_t)ps * N_NODES + q0 + lg * 4 + r) * C_DIM + lr] = o[r];
}

// ---------------------------------------------------------------------------
// K5: merge the NKS1 K-split partials per (branch, row) — plain sums.
// ---------------------------------------------------------------------------
__global__ __launch_bounds__(256) void combine1_kernel(
    const float* __restrict__ pl, const float* __restrict__ pacc,
    float* __restrict__ o1)
{
  const int q = blockIdx.x * 256 + threadIdx.x;
  const int b = blockIdx.y;
  float L = 0.f;
  f32x4 out0 = (f32x4){0,0,0,0}, out1 = (f32x4){0,0,0,0},
        out2 = (f32x4){0,0,0,0}, out3 = (f32x4){0,0,0,0};
#pragma unroll
  for (int ks = 0; ks < NKS1; ks++) {
    const size_t pidx = (size_t)(b * NKS1 + ks) * N_NODES + q;
    L += pl[pidx];
    const f32x4* pa = (const f32x4*)(pacc + pidx * C_DIM);
    out0 += pa[0]; out1 += pa[1]; out2 += pa[2]; out3 += pa[3];
  }
  float invL = 1.0f / L;
  f32x4* dst = (f32x4*)(o1 + ((size_t)b * N_NODES + q) * C_DIM);
  dst[0] = out0 * invL; dst[1] = out1 * invL; dst[2] = out2 * invL; dst[3] = out3 * invL;
}

// ---------------------------------------------------------------------------
// K6: add biases, softmax(g1)-weighted branch mix, log_softmax over 16.
// ---------------------------------------------------------------------------
__global__ __launch_bounds__(256) void final_kernel(
    const float* __restrict__ o1,
    const float* __restrict__ bl1, const float* __restrict__ bh1,
    const float* __restrict__ bm1,
    const float* __restrict__ g1, float* __restrict__ out)
{
  const int q = blockIdx.x * 256 + threadIdx.x;
  float ga = g1[0], gb = g1[1], gc = g1[2];
  float gm = fmaxf(ga, fmaxf(gb, gc));
  float e0 = expf(ga - gm), e1 = expf(gb - gm), e2 = expf(gc - gm);
  float ei = 1.0f / (e0 + e1 + e2);
  float w0 = e0 * ei, w1 = e1 * ei, w2 = e2 * ei;
  const size_t NC = (size_t)N_NODES * C_DIM;

  float v[16];
#pragma unroll
  for (int i = 0; i < 4; i++) {
    f32x4 a = ((const f32x4*)(o1 + (size_t)q * C_DIM))[i];
    f32x4 bA = ((const f32x4*)(o1 + NC + (size_t)q * C_DIM))[i];
    f32x4 c = ((const f32x4*)(o1 + 2 * NC + (size_t)q * C_DIM))[i];
    f32x4 xl = ((const f32x4*)bl1)[i];
    f32x4 xh = ((const f32x4*)bh1)[i];
    f32x4 xm = ((const f32x4*)bm1)[i];
#pragma unroll
    for (int j = 0; j < 4; j++)
      v[i * 4 + j] = w0 * (a[j] + xl[j]) + w1 * (bA[j] + xh[j]) + w2 * (c[j] + xm[j]);
  }
  float mx = -1e30f;
#pragma unroll
  for (int j = 0; j < 16; j++) mx = fmaxf(mx, v[j]);
  float se = 0.f;
#pragma unroll
  for (int j = 0; j < 16; j++) se += expf(v[j] - mx);
  float lse = mx + logf(se);
  f32x4* dst = (f32x4*)(out + (size_t)q * C_DIM);
#pragma unroll
  for (int i = 0; i < 4; i++) {
    f32x4 r;
#pragma unroll
    for (int j = 0; j < 4; j++) r[j] = v[i * 4 + j] - lse;
    dst[i] = r;
  }
}

// ---------------------------------------------------------------------------
extern "C" void kernel_launch(void* const* d_in, const int* in_sizes, int n_in,
                              void* d_out, int out_size, void* d_ws, size_t ws_size,
                              hipStream_t stream) {
  (void)in_sizes; (void)n_in; (void)out_size; (void)ws_size;
  const float* x     = (const float*)d_in[0];
  const float* adj_l = (const float*)d_in[1];
  const float* adj_h = (const float*)d_in[2];
  const float* adj_m = (const float*)d_in[3];
  const float* w_l0  = (const float*)d_in[4];
  const float* b_l0  = (const float*)d_in[5];
  const float* w_h0  = (const float*)d_in[6];
  const float* b_h0  = (const float*)d_in[7];
  const float* w_m0  = (const float*)d_in[8];
  const float* b_m0  = (const float*)d_in[9];
  const float* w_l1  = (const float*)d_in[10];
  const float* b_l1  = (const float*)d_in[11];
  const float* w_h1  = (const float*)d_in[12];
  const float* b_h1  = (const float*)d_in[13];
  const float* w_m1  = (const float*)d_in[14];
  const float* b_m1  = (const float*)d_in[15];
  const float* g0    = (const float*)d_in[16];
  const float* g1    = (const float*)d_in[17];
  float* out = (float*)d_out;

  char* ws = (char*)d_ws;
  // persistent:
  ushort* hn  = (ushort*)(ws);                  // [0, 3MB)
  ushort* hvT = (ushort*)(ws + (3u << 20));     // [3MB, 6MB)
  ushort* hn1b= (ushort*)(ws + (6u << 20));                 // 384KB
  ushort* hbT = (ushort*)(ws + (6u << 20) + (384u << 10));  // 384KB
  // phase A (layer-0 partials, dead after mix1):
  float*  pl0 = (float*)(ws + (12u << 20));                    // 384KB
  ushort* pO  = (ushort*)(ws + (12u << 20) + (512u << 10));    // 24MB (bf16)
  // phase B (layer-1 scratch), reuses phase-A region after mix1:
  float*  pl  = (float*)(ws + (12u << 20));                    // 384KB
  float*  pacc= (float*)(ws + (13u << 20));                    // 6MB
  float*  o1  = (float*)(ws + (20u << 20));                    // 768KB

  proj0_kernel<<<dim3(512), dim3(256), 0, stream>>>(x, w_l0, w_h0, w_m0, hn, hvT);
  flash0_kernel<<<dim3(32, NKS0, 3), dim3(512), 0, stream>>>(hn, hvT, adj_l, adj_h, adj_m,
                                                             pl0, pO);
  mix1_kernel<<<dim3(4096), dim3(128), 0, stream>>>(pl0, pO, b_l0, b_h0, b_m0,
                                                    w_l1, w_h1, w_m1, g0, hn1b, hbT);
  flash1_kernel<<<dim3(64, NKS1, 3), dim3(256), 0, stream>>>(hn1b, hbT, adj_l, adj_h, adj_m,
                                                             pl, pacc);
  combine1_kernel<<<dim3(16, 3), dim3(256), 0, stream>>>(pl, pacc, o1);
  final_kernel<<<dim3(16), dim3(256), 0, stream>>>(o1, b_l1, b_h1, b_m1, g1, out);
}